// Round 1
// baseline (787.706 us; speedup 1.0000x reference)
//
#include <hip/hip_runtime.h>

#define N_NODES 50000
#define N_EDGES 800000
#define D 64          // NODE_DIM == MSG_DIM
#define EDIM 4
#define IN_DIM 132    // 2*D + EDIM
#define H3 192        // 3*D

// ---------------- CSR build ----------------

__global__ void k_count(const int* __restrict__ dst, int* __restrict__ deg) {
    int e = blockIdx.x * blockDim.x + threadIdx.x;
    if (e < N_EDGES) atomicAdd(&deg[dst[e]], 1);
}

// Single-block exclusive scan of deg[N] -> offsets[N]
__global__ void k_scan(const int* __restrict__ deg, int* __restrict__ offsets) {
    __shared__ int sm[1024];
    __shared__ int carry_sm;
    if (threadIdx.x == 0) carry_sm = 0;
    __syncthreads();
    const int nchunk = (N_NODES + 1023) / 1024;
    for (int c = 0; c < nchunk; ++c) {
        int i = c * 1024 + threadIdx.x;
        int x = (i < N_NODES) ? deg[i] : 0;
        sm[threadIdx.x] = x;
        __syncthreads();
        // Hillis-Steele inclusive scan
        for (int s = 1; s < 1024; s <<= 1) {
            int v = (threadIdx.x >= s) ? sm[threadIdx.x - s] : 0;
            __syncthreads();
            sm[threadIdx.x] += v;
            __syncthreads();
        }
        if (i < N_NODES) offsets[i] = carry_sm + sm[threadIdx.x] - x; // exclusive
        __syncthreads();
        if (threadIdx.x == 0) carry_sm += sm[1023];
        __syncthreads();
    }
}

__global__ void k_fill(const int* __restrict__ dst, const int* __restrict__ offsets,
                       int* __restrict__ cursor, int* __restrict__ csr) {
    int e = blockIdx.x * blockDim.x + threadIdx.x;
    if (e < N_EDGES) {
        int d = dst[e];
        int pos = offsets[d] + atomicAdd(&cursor[d], 1);
        csr[pos] = e;
    }
}

// ---------------- per-round reduce: S[n] = sum_{e->n} hv[src_e]; (round0) Hsum[n] = sum he_e ----------------

template <int ROUND>
__global__ __launch_bounds__(256) void k_reduce(const float* __restrict__ hv,
                                                const float* __restrict__ he,
                                                const int* __restrict__ src,
                                                const int* __restrict__ csr,
                                                const int* __restrict__ offsets,
                                                const int* __restrict__ deg,
                                                float* __restrict__ S,
                                                float* __restrict__ Hsum) {
    int wave = (blockIdx.x * blockDim.x + threadIdx.x) >> 6;
    int lane = threadIdx.x & 63;
    if (wave >= N_NODES) return;
    const int n = wave;
    const int off = offsets[n];
    const int cnt = deg[n];
    float acc = 0.f;
    float hs = 0.f;
    for (int e = 0; e < cnt; ++e) {
        int ei = csr[off + e];
        int s = src[ei];
        acc += hv[s * D + lane];
        if (ROUND == 0 && lane < EDIM) hs += he[ei * EDIM + lane];
    }
    S[n * D + lane] = acc;
    if (ROUND == 0 && lane < EDIM) Hsum[n * EDIM + lane] = hs;
}

// ---------------- node update: a = S@Wa + deg*hv@Wb + Hsum@Wc + deg*b ; hv = GRU(a, hv) ----------------

#define NB 4  // nodes per wave

__global__ __launch_bounds__(256) void k_node(const float* __restrict__ hv_in,
                                              const float* __restrict__ S,
                                              const float* __restrict__ Hsum,
                                              const int* __restrict__ deg,
                                              const float* __restrict__ W_msg,
                                              const float* __restrict__ b_msg,
                                              const float* __restrict__ W_ih,
                                              const float* __restrict__ W_hh,
                                              const float* __restrict__ b_ih,
                                              const float* __restrict__ b_hh,
                                              float* __restrict__ hv_out, int t) {
    const int wave = (blockIdx.x * blockDim.x + threadIdx.x) >> 6;
    const int lane = threadIdx.x & 63;
    const int n0 = wave * NB;

    const float* Wm = W_msg + t * IN_DIM * D;
    const float* bm = b_msg + t * D;
    const float* Wi = W_ih + t * D * H3;
    const float* Wh = W_hh + t * D * H3;
    const float* bi = b_ih + t * H3;
    const float* bh = b_hh + t * H3;

    float hvv[NB], Sv[NB], degf[NB];
    float Hs0[NB], Hs1[NB], Hs2[NB], Hs3[NB];
    int nidx[NB];
    bool valid[NB];
#pragma unroll
    for (int nb = 0; nb < NB; ++nb) {
        int n = n0 + nb;
        valid[nb] = (n < N_NODES);
        int nc = valid[nb] ? n : 0;
        nidx[nb] = nc;
        hvv[nb] = hv_in[nc * D + lane];
        Sv[nb] = S[nc * D + lane];
        degf[nb] = (float)deg[nc];
        Hs0[nb] = Hsum[nc * 4 + 0];
        Hs1[nb] = Hsum[nc * 4 + 1];
        Hs2[nb] = Hsum[nc * 4 + 2];
        Hs3[nb] = Hsum[nc * 4 + 3];
    }

    const float bmj = bm[lane];
    float a[NB], t2[NB];
#pragma unroll
    for (int nb = 0; nb < NB; ++nb) { a[nb] = 0.f; t2[nb] = 0.f; }

    // a += S@Wa ; t2 += hv@Wb
    for (int k = 0; k < D; ++k) {
        float w1 = Wm[k * D + lane];
        float w2 = Wm[(D + k) * D + lane];
#pragma unroll
        for (int nb = 0; nb < NB; ++nb) {
            float sk = __shfl(Sv[nb], k);
            float hk = __shfl(hvv[nb], k);
            a[nb] = fmaf(sk, w1, a[nb]);
            t2[nb] = fmaf(hk, w2, t2[nb]);
        }
    }
    {
        float w30 = Wm[(2 * D + 0) * D + lane];
        float w31 = Wm[(2 * D + 1) * D + lane];
        float w32 = Wm[(2 * D + 2) * D + lane];
        float w33 = Wm[(2 * D + 3) * D + lane];
#pragma unroll
        for (int nb = 0; nb < NB; ++nb) {
            a[nb] += degf[nb] * (t2[nb] + bmj) + Hs0[nb] * w30 + Hs1[nb] * w31 +
                     Hs2[nb] * w32 + Hs3[nb] * w33;
        }
    }

    // GRU gates
    float gir[NB], giz[NB], gin[NB], ghr[NB], ghz[NB], ghn[NB];
    const float bir = bi[lane], biz = bi[D + lane], bin = bi[2 * D + lane];
    const float bhr = bh[lane], bhz = bh[D + lane], bhn = bh[2 * D + lane];
#pragma unroll
    for (int nb = 0; nb < NB; ++nb) {
        gir[nb] = bir; giz[nb] = biz; gin[nb] = bin;
        ghr[nb] = bhr; ghz[nb] = bhz; ghn[nb] = bhn;
    }
    for (int k = 0; k < D; ++k) {
        const float* wiRow = Wi + k * H3;
        const float* whRow = Wh + k * H3;
        float wir = wiRow[lane];
        float wiz = wiRow[D + lane];
        float win = wiRow[2 * D + lane];
        float whr = whRow[lane];
        float whz = whRow[D + lane];
        float whn = whRow[2 * D + lane];
#pragma unroll
        for (int nb = 0; nb < NB; ++nb) {
            float ak = __shfl(a[nb], k);
            float hk = __shfl(hvv[nb], k);
            gir[nb] = fmaf(ak, wir, gir[nb]);
            giz[nb] = fmaf(ak, wiz, giz[nb]);
            gin[nb] = fmaf(ak, win, gin[nb]);
            ghr[nb] = fmaf(hk, whr, ghr[nb]);
            ghz[nb] = fmaf(hk, whz, ghz[nb]);
            ghn[nb] = fmaf(hk, whn, ghn[nb]);
        }
    }

#pragma unroll
    for (int nb = 0; nb < NB; ++nb) {
        float r = 1.f / (1.f + __expf(-(gir[nb] + ghr[nb])));
        float z = 1.f / (1.f + __expf(-(giz[nb] + ghz[nb])));
        float nin = gin[nb] + r * ghn[nb];
        float nn = 2.f / (1.f + __expf(-2.f * nin)) - 1.f;  // tanh
        float outv = (1.f - z) * nn + z * hvv[nb];
        if (valid[nb]) hv_out[nidx[nb] * D + lane] = outv;
    }
}

// ---------------- launch ----------------

extern "C" void kernel_launch(void* const* d_in, const int* in_sizes, int n_in,
                              void* d_out, int out_size, void* d_ws, size_t ws_size,
                              hipStream_t stream) {
    const float* hv = (const float*)d_in[0];
    const float* he = (const float*)d_in[1];
    const float* W_msg = (const float*)d_in[2];
    const float* b_msg = (const float*)d_in[3];
    const float* W_ih = (const float*)d_in[4];
    const float* W_hh = (const float*)d_in[5];
    const float* b_ih = (const float*)d_in[6];
    const float* b_hh = (const float*)d_in[7];
    const int* src = (const int*)d_in[8];
    const int* dst = (const int*)d_in[9];
    float* out = (float*)d_out;

    char* p = (char*)d_ws;
    int* deg = (int*)p;        p += (size_t)N_NODES * sizeof(int);
    int* cursor = (int*)p;     p += (size_t)N_NODES * sizeof(int);
    int* offsets = (int*)p;    p += (size_t)N_NODES * sizeof(int);
    int* csr = (int*)p;        p += (size_t)N_EDGES * sizeof(int);
    float* Hsum = (float*)p;   p += (size_t)N_NODES * EDIM * sizeof(float);
    float* S = (float*)p;      p += (size_t)N_NODES * D * sizeof(float);
    float* hv_buf = (float*)p; p += (size_t)N_NODES * D * sizeof(float);

    hipMemsetAsync(deg, 0, N_NODES * sizeof(int), stream);
    hipMemsetAsync(cursor, 0, N_NODES * sizeof(int), stream);

    k_count<<<(N_EDGES + 255) / 256, 256, 0, stream>>>(dst, deg);
    k_scan<<<1, 1024, 0, stream>>>(deg, offsets);
    k_fill<<<(N_EDGES + 255) / 256, 256, 0, stream>>>(dst, offsets, cursor, csr);

    // round 0: read input hv, write hv_buf
    k_reduce<0><<<(N_NODES + 3) / 4, 256, 0, stream>>>(hv, he, src, csr, offsets, deg, S, Hsum);
    k_node<<<(N_NODES + 4 * NB - 1) / (4 * NB), 256, 0, stream>>>(
        hv, S, Hsum, deg, W_msg, b_msg, W_ih, W_hh, b_ih, b_hh, hv_buf, 0);

    // round 1: read hv_buf, write d_out
    k_reduce<1><<<(N_NODES + 3) / 4, 256, 0, stream>>>(hv_buf, he, src, csr, offsets, deg, S, Hsum);
    k_node<<<(N_NODES + 4 * NB - 1) / (4 * NB), 256, 0, stream>>>(
        hv_buf, S, Hsum, deg, W_msg, b_msg, W_ih, W_hh, b_ih, b_hh, out, 1);
}

// Round 2
// 429.799 us; speedup vs baseline: 1.8327x; 1.8327x over previous
//
#include <hip/hip_runtime.h>

#define N_NODES 50000
#define N_EDGES 800000
#define D 64          // NODE_DIM == MSG_DIM
#define EDIM 4
#define IN_DIM 132    // 2*D + EDIM
#define H3 192        // 3*D
#define PAD 72        // LDS row stride (floats): 288B, 16B-aligned rows, conflict-mitigating

// ---------------- CSR build ----------------

__global__ void k_count(const int* __restrict__ dst, int* __restrict__ deg) {
    int e = blockIdx.x * blockDim.x + threadIdx.x;
    if (e < N_EDGES) atomicAdd(&deg[dst[e]], 1);
}

// 3-stage block scan: partial per-block exclusive scan + block sums
__global__ __launch_bounds__(256) void k_scan1(const int* __restrict__ deg,
                                               int* __restrict__ offsets,
                                               int* __restrict__ bsum) {
    __shared__ int sm[256];
    int tid = threadIdx.x;
    int i = blockIdx.x * 256 + tid;
    int x = (i < N_NODES) ? deg[i] : 0;
    sm[tid] = x;
    __syncthreads();
    for (int s = 1; s < 256; s <<= 1) {
        int v = (tid >= s) ? sm[tid - s] : 0;
        __syncthreads();
        sm[tid] += v;
        __syncthreads();
    }
    if (i < N_NODES) offsets[i] = sm[tid] - x;  // block-local exclusive
    if (tid == 255) bsum[blockIdx.x] = sm[255];
}

__global__ __launch_bounds__(256) void k_scan2(const int* __restrict__ bsum,
                                               int* __restrict__ boff, int nblk) {
    __shared__ int sm[256];
    int tid = threadIdx.x;
    int x = (tid < nblk) ? bsum[tid] : 0;
    sm[tid] = x;
    __syncthreads();
    for (int s = 1; s < 256; s <<= 1) {
        int v = (tid >= s) ? sm[tid - s] : 0;
        __syncthreads();
        sm[tid] += v;
        __syncthreads();
    }
    if (tid < nblk) boff[tid] = sm[tid] - x;  // exclusive
}

__global__ __launch_bounds__(256) void k_scan3(int* __restrict__ offsets,
                                               const int* __restrict__ boff) {
    int i = blockIdx.x * 256 + threadIdx.x;
    if (i < N_NODES) offsets[i] += boff[blockIdx.x];
}

__global__ void k_fill(const int* __restrict__ src, const int* __restrict__ dst,
                       const int* __restrict__ offsets, int* __restrict__ cursor,
                       int* __restrict__ csr_src, int* __restrict__ csr_eid) {
    int e = blockIdx.x * blockDim.x + threadIdx.x;
    if (e < N_EDGES) {
        int d = dst[e];
        int pos = offsets[d] + atomicAdd(&cursor[d], 1);
        csr_src[pos] = src[e];
        csr_eid[pos] = e;
    }
}

// ---------------- reduce: S[n] = sum_{e->n} hv[src_e]; (round0) Hsum[n] = sum he_e --------
// wave per node; 4 edges in flight (lane>>4), 16 lanes x float4 cover the 64-dim row.

template <int ROUND>
__global__ __launch_bounds__(256) void k_reduce(const float* __restrict__ hv,
                                                const float* __restrict__ he,
                                                const int* __restrict__ csr_src,
                                                const int* __restrict__ csr_eid,
                                                const int* __restrict__ offsets,
                                                const int* __restrict__ deg,
                                                float* __restrict__ S,
                                                float* __restrict__ Hsum) {
    int wave = (blockIdx.x * blockDim.x + threadIdx.x) >> 6;
    if (wave >= N_NODES) return;
    int lane = threadIdx.x & 63;
    int g = lane >> 4;   // edge slot 0..3
    int c = lane & 15;   // float4 chunk of the row
    const int off = offsets[wave];
    const int cnt = deg[wave];
    float4 acc = make_float4(0.f, 0.f, 0.f, 0.f);
    float4 hacc = make_float4(0.f, 0.f, 0.f, 0.f);
    for (int e = g; e < cnt; e += 4) {
        int sn = csr_src[off + e];
        float4 v = ((const float4*)(hv + (size_t)sn * D))[c];
        acc.x += v.x; acc.y += v.y; acc.z += v.z; acc.w += v.w;
        if (ROUND == 0 && c == 0) {
            int eid = csr_eid[off + e];
            float4 h = *(const float4*)(he + (size_t)eid * EDIM);
            hacc.x += h.x; hacc.y += h.y; hacc.z += h.z; hacc.w += h.w;
        }
    }
    // butterfly sum across the 4 edge-slot groups (xor 16, 32 keeps c fixed)
    acc.x += __shfl_xor(acc.x, 16); acc.y += __shfl_xor(acc.y, 16);
    acc.z += __shfl_xor(acc.z, 16); acc.w += __shfl_xor(acc.w, 16);
    acc.x += __shfl_xor(acc.x, 32); acc.y += __shfl_xor(acc.y, 32);
    acc.z += __shfl_xor(acc.z, 32); acc.w += __shfl_xor(acc.w, 32);
    if (ROUND == 0) {
        hacc.x += __shfl_xor(hacc.x, 16); hacc.y += __shfl_xor(hacc.y, 16);
        hacc.z += __shfl_xor(hacc.z, 16); hacc.w += __shfl_xor(hacc.w, 16);
        hacc.x += __shfl_xor(hacc.x, 32); hacc.y += __shfl_xor(hacc.y, 32);
        hacc.z += __shfl_xor(hacc.z, 32); hacc.w += __shfl_xor(hacc.w, 32);
    }
    if (g == 0) ((float4*)(S + (size_t)wave * D))[c] = acc;
    if (ROUND == 0 && lane == 0) *(float4*)(Hsum + (size_t)wave * EDIM) = hacc;
}

// ---------------- node update: LDS-tiled register-tiled fp32 GEMM ----------------
// Block: 256 threads, 64 nodes. XT[k][n] (k-major, PAD=72).
// rows 0..63: S (GEMM1) then a (GEMM2, overwritten); rows 64..127: hv; 128..131: Hsum.
// GEMM1: acc1 = S@Wa + Hsum@Wc, acc2 = hv@Wb;  a = acc1 + deg*(acc2 + b_msg)
// GEMM2: thread's j-set = {j0.., j0+64.., j0+128..} so (r,z,n) triples are thread-local.

__global__ __launch_bounds__(256) void k_node(const float* __restrict__ hv_in,
                                              const float* __restrict__ S,
                                              const float* __restrict__ Hsum,
                                              const int* __restrict__ deg,
                                              const float* __restrict__ W_msg,
                                              const float* __restrict__ b_msg,
                                              const float* __restrict__ W_ih,
                                              const float* __restrict__ W_hh,
                                              const float* __restrict__ b_ih,
                                              const float* __restrict__ b_hh,
                                              float* __restrict__ hv_out, int t) {
    __shared__ __align__(16) float XT[IN_DIM * PAD];
    __shared__ float degf_sm[64];

    const int tid = threadIdx.x;
    const int n_base = blockIdx.x * 64;

    // ---- stage S, hv, Hsum, deg into LDS (transposed) ----
    {
        int nl = tid >> 2;  // local node 0..63
        int c4 = tid & 3;   // 16-float chunk
        int n = n_base + nl;
        if (n >= N_NODES) n = N_NODES - 1;
        const float4* Srow = (const float4*)(S + (size_t)n * D);
        const float4* Hrow = (const float4*)(hv_in + (size_t)n * D);
#pragma unroll
        for (int i = 0; i < 4; ++i) {
            int k = c4 * 16 + i * 4;
            float4 sv = Srow[c4 * 4 + i];
            XT[(k + 0) * PAD + nl] = sv.x;
            XT[(k + 1) * PAD + nl] = sv.y;
            XT[(k + 2) * PAD + nl] = sv.z;
            XT[(k + 3) * PAD + nl] = sv.w;
            float4 hvv = Hrow[c4 * 4 + i];
            XT[(64 + k + 0) * PAD + nl] = hvv.x;
            XT[(64 + k + 1) * PAD + nl] = hvv.y;
            XT[(64 + k + 2) * PAD + nl] = hvv.z;
            XT[(64 + k + 3) * PAD + nl] = hvv.w;
        }
        if (c4 == 0) {
            float4 hs = *(const float4*)(Hsum + (size_t)n * EDIM);
            XT[(128) * PAD + nl] = hs.x;
            XT[(129) * PAD + nl] = hs.y;
            XT[(130) * PAD + nl] = hs.z;
            XT[(131) * PAD + nl] = hs.w;
        }
        if (c4 == 1) degf_sm[nl] = (float)deg[n];
    }
    __syncthreads();

    const int jg = tid & 15, ng = tid >> 4;
    const int n0 = ng * 4;  // local node base (0..60)
    const int j0 = jg * 4;  // feature base (0..60)

    // ---- GEMM1 ----
    float acc1[4][4], acc2[4][4];
#pragma unroll
    for (int a = 0; a < 4; ++a)
#pragma unroll
        for (int b = 0; b < 4; ++b) { acc1[a][b] = 0.f; acc2[a][b] = 0.f; }

    const float* Wm = W_msg + (size_t)t * IN_DIM * D;
#pragma unroll 4
    for (int k = 0; k < 64; ++k) {
        float4 A = *(const float4*)(&XT[k * PAD + n0]);
        float4 B = *(const float4*)(Wm + k * D + j0);
        float Aa[4] = {A.x, A.y, A.z, A.w};
        float Bb[4] = {B.x, B.y, B.z, B.w};
#pragma unroll
        for (int ni = 0; ni < 4; ++ni)
#pragma unroll
            for (int ji = 0; ji < 4; ++ji)
                acc1[ni][ji] = fmaf(Aa[ni], Bb[ji], acc1[ni][ji]);
    }
#pragma unroll 4
    for (int k = 64; k < 128; ++k) {
        float4 A = *(const float4*)(&XT[k * PAD + n0]);
        float4 B = *(const float4*)(Wm + k * D + j0);
        float Aa[4] = {A.x, A.y, A.z, A.w};
        float Bb[4] = {B.x, B.y, B.z, B.w};
#pragma unroll
        for (int ni = 0; ni < 4; ++ni)
#pragma unroll
            for (int ji = 0; ji < 4; ++ji)
                acc2[ni][ji] = fmaf(Aa[ni], Bb[ji], acc2[ni][ji]);
    }
#pragma unroll
    for (int k = 128; k < 132; ++k) {
        float4 A = *(const float4*)(&XT[k * PAD + n0]);
        float4 B = *(const float4*)(Wm + k * D + j0);
        float Aa[4] = {A.x, A.y, A.z, A.w};
        float Bb[4] = {B.x, B.y, B.z, B.w};
#pragma unroll
        for (int ni = 0; ni < 4; ++ni)
#pragma unroll
            for (int ji = 0; ji < 4; ++ji)
                acc1[ni][ji] = fmaf(Aa[ni], Bb[ji], acc1[ni][ji]);
    }

    float4 bm = *(const float4*)(b_msg + (size_t)t * D + j0);
    float bmv[4] = {bm.x, bm.y, bm.z, bm.w};
    float av[4][4];
#pragma unroll
    for (int ni = 0; ni < 4; ++ni) {
        float dg = degf_sm[n0 + ni];
#pragma unroll
        for (int ji = 0; ji < 4; ++ji)
            av[ni][ji] = acc1[ni][ji] + dg * (acc2[ni][ji] + bmv[ji]);
    }
    __syncthreads();  // everyone done reading rows 0..63
    // write a^T into XT rows 0..63
#pragma unroll
    for (int ni = 0; ni < 4; ++ni)
#pragma unroll
        for (int ji = 0; ji < 4; ++ji)
            XT[(j0 + ji) * PAD + (n0 + ni)] = av[ni][ji];
    __syncthreads();

    // ---- GEMM2: gi (from a) and gh (from hv) ----
    const float* Wi = W_ih + (size_t)t * D * H3;
    const float* Wh = W_hh + (size_t)t * D * H3;
    const float* bi = b_ih + (size_t)t * H3;
    const float* bh = b_hh + (size_t)t * H3;

    float4 biR = *(const float4*)(bi + j0);
    float4 biZ = *(const float4*)(bi + 64 + j0);
    float4 biN = *(const float4*)(bi + 128 + j0);
    float4 bhR = *(const float4*)(bh + j0);
    float4 bhZ = *(const float4*)(bh + 64 + j0);
    float4 bhN = *(const float4*)(bh + 128 + j0);
    float accR[4][4], accZ[4][4], accIN[4][4], accHN[4][4];
    {
        float r0[4] = {biR.x + bhR.x, biR.y + bhR.y, biR.z + bhR.z, biR.w + bhR.w};
        float z0[4] = {biZ.x + bhZ.x, biZ.y + bhZ.y, biZ.z + bhZ.z, biZ.w + bhZ.w};
        float in0[4] = {biN.x, biN.y, biN.z, biN.w};
        float hn0[4] = {bhN.x, bhN.y, bhN.z, bhN.w};
#pragma unroll
        for (int ni = 0; ni < 4; ++ni)
#pragma unroll
            for (int ji = 0; ji < 4; ++ji) {
                accR[ni][ji] = r0[ji];
                accZ[ni][ji] = z0[ji];
                accIN[ni][ji] = in0[ji];
                accHN[ni][ji] = hn0[ji];
            }
    }

#pragma unroll 2
    for (int k = 0; k < 64; ++k) {  // A = a rows
        float4 A = *(const float4*)(&XT[k * PAD + n0]);
        const float* wrow = Wi + k * H3;
        float4 wR = *(const float4*)(wrow + j0);
        float4 wZ = *(const float4*)(wrow + 64 + j0);
        float4 wN = *(const float4*)(wrow + 128 + j0);
        float Aa[4] = {A.x, A.y, A.z, A.w};
        float R[4] = {wR.x, wR.y, wR.z, wR.w};
        float Z[4] = {wZ.x, wZ.y, wZ.z, wZ.w};
        float Nn[4] = {wN.x, wN.y, wN.z, wN.w};
#pragma unroll
        for (int ni = 0; ni < 4; ++ni)
#pragma unroll
            for (int ji = 0; ji < 4; ++ji) {
                accR[ni][ji] = fmaf(Aa[ni], R[ji], accR[ni][ji]);
                accZ[ni][ji] = fmaf(Aa[ni], Z[ji], accZ[ni][ji]);
                accIN[ni][ji] = fmaf(Aa[ni], Nn[ji], accIN[ni][ji]);
            }
    }
#pragma unroll 2
    for (int k = 0; k < 64; ++k) {  // A = hv rows
        float4 A = *(const float4*)(&XT[(64 + k) * PAD + n0]);
        const float* wrow = Wh + k * H3;
        float4 wR = *(const float4*)(wrow + j0);
        float4 wZ = *(const float4*)(wrow + 64 + j0);
        float4 wN = *(const float4*)(wrow + 128 + j0);
        float Aa[4] = {A.x, A.y, A.z, A.w};
        float R[4] = {wR.x, wR.y, wR.z, wR.w};
        float Z[4] = {wZ.x, wZ.y, wZ.z, wZ.w};
        float Nn[4] = {wN.x, wN.y, wN.z, wN.w};
#pragma unroll
        for (int ni = 0; ni < 4; ++ni)
#pragma unroll
            for (int ji = 0; ji < 4; ++ji) {
                accR[ni][ji] = fmaf(Aa[ni], R[ji], accR[ni][ji]);
                accZ[ni][ji] = fmaf(Aa[ni], Z[ji], accZ[ni][ji]);
                accHN[ni][ji] = fmaf(Aa[ni], Nn[ji], accHN[ni][ji]);
            }
    }

    // ---- GRU combine + store ----
#pragma unroll
    for (int ni = 0; ni < 4; ++ni) {
        int n = n_base + n0 + ni;
        if (n < N_NODES) {
            float4 hv4 = *(const float4*)(hv_in + (size_t)n * D + j0);
            float hvv[4] = {hv4.x, hv4.y, hv4.z, hv4.w};
            float o[4];
#pragma unroll
            for (int ji = 0; ji < 4; ++ji) {
                float r = 1.f / (1.f + __expf(-accR[ni][ji]));
                float z = 1.f / (1.f + __expf(-accZ[ni][ji]));
                float nin = accIN[ni][ji] + r * accHN[ni][ji];
                float nn = 2.f / (1.f + __expf(-2.f * nin)) - 1.f;
                o[ji] = (1.f - z) * nn + z * hvv[ji];
            }
            *(float4*)(hv_out + (size_t)n * D + j0) = make_float4(o[0], o[1], o[2], o[3]);
        }
    }
}

// ---------------- launch ----------------

extern "C" void kernel_launch(void* const* d_in, const int* in_sizes, int n_in,
                              void* d_out, int out_size, void* d_ws, size_t ws_size,
                              hipStream_t stream) {
    const float* hv = (const float*)d_in[0];
    const float* he = (const float*)d_in[1];
    const float* W_msg = (const float*)d_in[2];
    const float* b_msg = (const float*)d_in[3];
    const float* W_ih = (const float*)d_in[4];
    const float* W_hh = (const float*)d_in[5];
    const float* b_ih = (const float*)d_in[6];
    const float* b_hh = (const float*)d_in[7];
    const int* src = (const int*)d_in[8];
    const int* dst = (const int*)d_in[9];
    float* out = (float*)d_out;

    char* p = (char*)d_ws;
    int* deg = (int*)p;        p += (size_t)N_NODES * sizeof(int);
    int* cursor = (int*)p;     p += (size_t)N_NODES * sizeof(int);
    int* offsets = (int*)p;    p += (size_t)N_NODES * sizeof(int);
    int* bsum = (int*)p;       p += 256 * sizeof(int);
    int* boff = (int*)p;       p += 256 * sizeof(int);
    int* csr_src = (int*)p;    p += (size_t)N_EDGES * sizeof(int);
    float* Hsum = (float*)p;   p += (size_t)N_NODES * EDIM * sizeof(float);
    float* S = (float*)p;      p += (size_t)N_NODES * D * sizeof(float);
    float* hv_buf = (float*)p; p += (size_t)N_NODES * D * sizeof(float);
    // csr_eid aliases hv_buf: consumed by k_reduce<0> before k_node writes hv_buf
    int* csr_eid = (int*)hv_buf;

    const int NBLK = (N_NODES + 255) / 256;  // 196

    hipMemsetAsync(deg, 0, N_NODES * sizeof(int), stream);
    hipMemsetAsync(cursor, 0, N_NODES * sizeof(int), stream);

    k_count<<<(N_EDGES + 255) / 256, 256, 0, stream>>>(dst, deg);
    k_scan1<<<NBLK, 256, 0, stream>>>(deg, offsets, bsum);
    k_scan2<<<1, 256, 0, stream>>>(bsum, boff, NBLK);
    k_scan3<<<NBLK, 256, 0, stream>>>(offsets, boff);
    k_fill<<<(N_EDGES + 255) / 256, 256, 0, stream>>>(src, dst, offsets, cursor, csr_src, csr_eid);

    const int RBLK = (N_NODES * 64 + 255) / 256;      // wave per node
    const int GBLK = (N_NODES + 63) / 64;             // 64 nodes per block

    // round 0: read input hv, write hv_buf
    k_reduce<0><<<RBLK, 256, 0, stream>>>(hv, he, csr_src, csr_eid, offsets, deg, S, Hsum);
    k_node<<<GBLK, 256, 0, stream>>>(hv, S, Hsum, deg, W_msg, b_msg, W_ih, W_hh, b_ih, b_hh, hv_buf, 0);

    // round 1: read hv_buf, write d_out
    k_reduce<1><<<RBLK, 256, 0, stream>>>(hv_buf, he, csr_src, csr_eid, offsets, deg, S, Hsum);
    k_node<<<GBLK, 256, 0, stream>>>(hv_buf, S, Hsum, deg, W_msg, b_msg, W_ih, W_hh, b_ih, b_hh, out, 1);
}